// Round 9
// baseline (413.875 us; speedup 1.0000x reference)
//
#include <hip/hip_runtime.h>

// Problem constants (fixed by the reference):
#define NN    40000
#define EE    640000
#define INC   128
#define HID   256
#define OUTC  10
#define GG    64
#define CAP   64        // CSR slot capacity per node (max in-degree << 64 for E/N=16)

typedef unsigned short u16;
typedef __attribute__((ext_vector_type(8))) short short8;   // 8 bf16 (4 VGPRs)
typedef __attribute__((ext_vector_type(4))) float f32x4;    // MFMA acc

__device__ __forceinline__ float bf2f(u16 h) {
    return __uint_as_float(((unsigned)h) << 16);
}
__device__ __forceinline__ u16 f2bf(float f) {   // round-to-nearest-even
    unsigned u = __float_as_uint(f);
    unsigned r = u + 0x7FFFu + ((u >> 16) & 1u);
    return (u16)(r >> 16);
}

// async global->LDS, 16 B per lane (mgemm staging only — R21's gather-to-LDS
// agg FAILED correctness; DO NOT RETRY).
__device__ __forceinline__ void gload_lds16(const u16* g, u16* l) {
    __builtin_amdgcn_global_load_lds(
        (const __attribute__((address_space(1))) unsigned int*)g,
        (__attribute__((address_space(3))) unsigned int*)l,
        16, 0, 0);
}

// ---------------------------------------------------------------------------
// build: ONE kernel, two independent segments:
//  [0, e4)       : edge pass — rank = cnt[dst]++ ; col[dst*CAP+rank]=src
//  [e4, e4+WTOT) : weight transpose + bf16 hi/lo split
#define WTOT (INC * HID + HID * HID)
__global__ void build_kernel(const int* __restrict__ src, const int* __restrict__ dst,
                             int* __restrict__ cnt, u16* __restrict__ col, int e4,
                             const float* __restrict__ W1, u16* __restrict__ w1h,
                             u16* __restrict__ w1l,
                             const float* __restrict__ W2, u16* __restrict__ w2h,
                             u16* __restrict__ w2l) {
    int i = blockIdx.x * blockDim.x + threadIdx.x;
    if (i < e4) {
        int4 d = ((const int4*)dst)[i];
        int4 s = ((const int4*)src)[i];
        int r0 = atomicAdd(&cnt[d.x], 1);
        int r1 = atomicAdd(&cnt[d.y], 1);
        int r2 = atomicAdd(&cnt[d.z], 1);
        int r3 = atomicAdd(&cnt[d.w], 1);
        if (r0 < CAP) col[(d.x << 6) + r0] = (u16)s.x;
        if (r1 < CAP) col[(d.y << 6) + r1] = (u16)s.y;
        if (r2 < CAP) col[(d.z << 6) + r2] = (u16)s.z;
        if (r3 < CAP) col[(d.w << 6) + r3] = (u16)s.w;
    } else if (i < e4 + WTOT) {
        int idx = i - e4;
        const float* W; u16 *Th, *Tl; int K;
        if (idx < INC * HID) { W = W1; Th = w1h; Tl = w1l; K = INC; }
        else { W = W2; Th = w2h; Tl = w2l; K = HID; idx -= INC * HID; }
        int k = idx >> 8;          // /256
        int n = idx & 255;
        float w = W[idx];          // idx == k*256 + n (row-major)
        u16 h = f2bf(w);
        float r = w - bf2f(h);
        Th[(size_t)n * K + k] = h;
        Tl[(size_t)n * K + k] = f2bf(r);
    }
}

// ---------------------------------------------------------------------------
// xs = bf16(rsqrt(cnt[n]+1) * x[n]) — pre-scaled features (R22). Runs after
// build (cnt final).
__global__ __launch_bounds__(256) void xscale_kernel(
    const float* __restrict__ x, const int* __restrict__ cnt,
    u16* __restrict__ xs, int total4) {
    int j = blockIdx.x * blockDim.x + threadIdx.x;   // one float4 per thread
    if (j >= total4) return;
    int n = j >> 5;                                  // 32 float4 per 128-row
    float dn = rsqrtf((float)(cnt[n] + 1));
    float4 v = ((const float4*)x)[j];
    ushort4 o;
    o.x = f2bf(v.x * dn); o.y = f2bf(v.y * dn);
    o.z = f2bf(v.z * dn); o.w = f2bf(v.w * dn);
    ((ushort4*)xs)[j] = o;
}

// ---------------------------------------------------------------------------
// MFMA GEMM (R20 PROVEN — do not revert):
// C[M, 256] = A[M,K](bf16) @ (Wh+Wl)[K,256] (W stored transposed [256][K] hi/lo).
//  MODE 0: store bf16(rsqrt(cnt[m]+1)*v) to Cout  (layer 1)
//  MODE 1: accumulate v into pooled[batch[m]][n]  (layer 2 + pool phase 1)
// FAILED, do not retry: R16 BM=64; R19 reg-staged LDS double-buffer.
#define BM 128
#define BN 128
#define BK 32
#define PGL 8    // max local graphs per 128-row tile (avg graph = 625 nodes)

template<int MODE>
__global__ __launch_bounds__(256) void mgemm_kernel(
    const u16* __restrict__ A,   // [M,K] bf16
    const u16* __restrict__ Bh,  // [256,K] bf16 (W^T hi)
    const u16* __restrict__ Bl,  // [256,K] bf16 (W^T lo)
    const float* __restrict__ bias,
    const int* __restrict__ cnt,
    u16* __restrict__ Cout,
    const int* __restrict__ batch, float* __restrict__ pooled,
    int M, int K)
{
    __shared__ __align__(16) u16 As [BM * BK];   // 8 KB, linear [row][chunk4]
    __shared__ __align__(16) u16 Bhs[BN * BK];   // 8 KB
    __shared__ __align__(16) u16 Bls[BN * BK];   // 8 KB
    __shared__ float ptile[MODE == 1 ? PGL * BN : 1];   // 4 KB in MODE 1 only

    const int tid  = threadIdx.x;
    const int lane = tid & 63;
    const int wave = tid >> 6;
    const int ln   = lane & 15;        // col within 16x16 tile
    const int qd   = lane >> 4;        // quad: k-unit for A/B frags, row-quad for C
    const int wm   = (wave & 1) * 64;  // wave m-offset in tile
    const int wn   = (wave >> 1) * 64; // wave n-offset in tile
    const int m0   = blockIdx.x * BM;
    const int n0   = blockIdx.y * BN;

    f32x4 acc[4][4];
#pragma unroll
    for (int i = 0; i < 4; ++i)
#pragma unroll
        for (int j = 0; j < 4; ++j) acc[i][j] = (f32x4)(0.0f);

    if (MODE == 1) {
        for (int t = tid; t < PGL * BN; t += 256) ptile[t] = 0.0f;
    }

    // staging lane roles: each wave-load covers 16 rows x 64 B (1 KB LDS)
    const int rl = lane >> 2;          // row within 16-row group
    const int su = lane & 3;           // 16B chunk slot within row
    // frag-read swizzle (uniform across t since wm, t*16 are mult. of 16)
    const int fsw = (qd ^ (ln & 3) ^ ((ln >> 2) & 3)) * 8;

    for (int k0 = 0; k0 < K; k0 += BK) {
        // ---- stage chunk k0: 6 async wave-loads, no VGPR round trip ----
#pragma unroll
        for (int L = 0; L < 2; ++L) {
            int rloc = (wave * 2 + L) * 16 + rl;            // 0..127
            int sw   = (su ^ (rloc & 3) ^ ((rloc >> 2) & 3)) * 8;
            int ga   = m0 + rloc; if (ga >= M) ga = M - 1;  // clamp; rows>=M never read back
            gload_lds16(A  + (size_t)ga * K        + k0 + sw, As  + (size_t)(wave * 2 + L) * 512);
            gload_lds16(Bh + (size_t)(n0 + rloc) * K + k0 + sw, Bhs + (size_t)(wave * 2 + L) * 512);
            gload_lds16(Bl + (size_t)(n0 + rloc) * K + k0 + sw, Bls + (size_t)(wave * 2 + L) * 512);
        }
        __syncthreads();   // drains vmcnt(0): tiles ready

        // ---- fragments + MFMA ----
        short8 af[4], bfh[4], bfl[4];
#pragma unroll
        for (int t = 0; t < 4; ++t) {
            af[t]  = *(const short8*)(As  + (wm + t * 16 + ln) * BK + fsw);
            bfh[t] = *(const short8*)(Bhs + (wn + t * 16 + ln) * BK + fsw);
            bfl[t] = *(const short8*)(Bls + (wn + t * 16 + ln) * BK + fsw);
        }
#pragma unroll
        for (int ti = 0; ti < 4; ++ti)
#pragma unroll
            for (int tj = 0; tj < 4; ++tj) {
                acc[ti][tj] = __builtin_amdgcn_mfma_f32_16x16x32_bf16(
                    af[ti], bfh[tj], acc[ti][tj], 0, 0, 0);
                acc[ti][tj] = __builtin_amdgcn_mfma_f32_16x16x32_bf16(
                    af[ti], bfl[tj], acc[ti][tj], 0, 0, 0);
            }
        __syncthreads();   // frag reads done before next chunk overwrites
    }

    // ---- epilogue: C layout col=lane&15, row=qd*4+reg ----
    float bcol[4];
#pragma unroll
    for (int tj = 0; tj < 4; ++tj) bcol[tj] = bias[n0 + wn + tj * 16 + ln];

    if (MODE == 0) {
#pragma unroll
        for (int ti = 0; ti < 4; ++ti) {
#pragma unroll
            for (int r = 0; r < 4; ++r) {
                int row = m0 + wm + ti * 16 + qd * 4 + r;
                if (row < M) {
                    float dm = rsqrtf((float)(cnt[row] + 1));
                    u16* crow = Cout + (size_t)row * HID;
#pragma unroll
                    for (int tj = 0; tj < 4; ++tj) {
                        float v = fmaxf(acc[ti][tj][r] + bcol[tj], 0.0f);
                        crow[n0 + wn + tj * 16 + ln] = f2bf(v * dm);
                    }
                }
            }
        }
    } else {
        // cache graph ids of this thread's 16 rows
        int bg[16];
#pragma unroll
        for (int ti = 0; ti < 4; ++ti)
#pragma unroll
            for (int r = 0; r < 4; ++r) {
                int row = m0 + wm + ti * 16 + qd * 4 + r;
                bg[ti * 4 + r] = (row < M) ? batch[row] : -1;
            }
        const int g_lo = batch[m0];
        const int g_hi = batch[min(m0 + BM, M) - 1];
        for (int g = g_lo; g <= g_hi; ++g) {
            float cs[4] = {0.0f, 0.0f, 0.0f, 0.0f};
#pragma unroll
            for (int ti = 0; ti < 4; ++ti)
#pragma unroll
                for (int r = 0; r < 4; ++r)
                    if (bg[ti * 4 + r] == g) {
#pragma unroll
                        for (int tj = 0; tj < 4; ++tj)
                            cs[tj] += fmaxf(acc[ti][tj][r] + bcol[tj], 0.0f);
                    }
            // fold the 4 qd lanes holding the same column (lane bits 16, 32)
#pragma unroll
            for (int tj = 0; tj < 4; ++tj) {
                cs[tj] += __shfl_xor(cs[tj], 16);
                cs[tj] += __shfl_xor(cs[tj], 32);
            }
            if (qd == 0) {
                int gl = g - g_lo;
#pragma unroll
                for (int tj = 0; tj < 4; ++tj) {
                    int c = wn + tj * 16 + ln;
                    if (gl < PGL) atomicAdd(&ptile[gl * BN + c], cs[tj]);
                    else atomicAdd(&pooled[(size_t)g * HID + n0 + c], cs[tj]);
                }
            }
        }
        __syncthreads();
        const int g0 = batch[m0];
        for (int t = tid; t < PGL * BN; t += 256) {
            float v = ptile[t];
            if (v != 0.0f) {
                int gl = t / BN, c = t % BN;
                atomicAdd(&pooled[(size_t)(g0 + gl) * HID + n0 + c], v);
            }
        }
    }
}

// ---------------------------------------------------------------------------
// agg1 (layer 1): PROVEN R22 wave-per-node gather (do not touch).
// out[n] = bf16(rsqrt(cnt[n]+1) * sum_items xs[idx]).
// Failed/neutral (do not retry): R8 UFx2, R10 2-waves/node, R13 src-partition,
// R19 shfl-hoist, R21 gather-to-LDS (broken), R23 %8-slicing (mapping wrong).
template<int F>
__global__ __launch_bounds__(256) void agg_kernel(
    const u16* __restrict__ hs, const int* __restrict__ cnt,
    const u16* __restrict__ col, u16* __restrict__ out, int n_nodes)
{
    constexpr int L  = F / 8;                   // lanes per item (16 or 32)
    constexpr int G  = 64 / L;                  // items per batch (4 or 2)
    constexpr int UF = 16 / G;                  // batches per iteration
    const int lane = threadIdx.x & 63;
    const int n    = (blockIdx.x * blockDim.x + threadIdx.x) >> 6;  // wave id
    if (n >= n_nodes) return;
    const int li = lane % L;
    const int gi = lane / L;

    const int base0 = n << 6;                   // n*CAP
    const int total = 1 + cnt[n];               // self + edges

    float acc[8];
#pragma unroll
    for (int i = 0; i < 8; ++i) acc[i] = 0.0f;

    for (int base = 0; base < total; base += G * UF) {
        int  idxs[UF];
        bool valid[UF];
#pragma unroll
        for (int u = 0; u < UF; ++u) {
            int it = base + u * G + gi;
            valid[u] = (it < total);
            idxs[u] = 0;
            if (valid[u]) idxs[u] = (it == 0) ? n : (int)col[base0 + it - 1];
        }
        uint4 w[UF];
#pragma unroll
        for (int u = 0; u < UF; ++u)
            if (valid[u])
                w[u] = *(const uint4*)(hs + (size_t)idxs[u] * F + li * 8);
#pragma unroll
        for (int u = 0; u < UF; ++u)
            if (valid[u]) {
                unsigned uu[4] = {w[u].x, w[u].y, w[u].z, w[u].w};
#pragma unroll
                for (int q = 0; q < 4; ++q) {
                    acc[2 * q]     += __uint_as_float(uu[q] << 16);
                    acc[2 * q + 1] += __uint_as_float(uu[q] & 0xFFFF0000u);
                }
            }
    }

#pragma unroll
    for (int off = 32; off >= L; off >>= 1)
#pragma unroll
        for (int i = 0; i < 8; ++i)
            acc[i] += __shfl_xor(acc[i], off);

    if (gi == 0) {
        float d = rsqrtf((float)total);
        unsigned r[4];
#pragma unroll
        for (int q = 0; q < 4; ++q) {
            unsigned l16 = (unsigned)f2bf(acc[2 * q] * d);
            unsigned h16 = (unsigned)f2bf(acc[2 * q + 1] * d);
            r[q] = l16 | (h16 << 16);
        }
        *(uint4*)(out + (size_t)n * F + li * 8) = make_uint4(r[0], r[1], r[2], r[3]);
    }
}

// ---------------------------------------------------------------------------
// R25: agg2 XCC-pinned sliced gather, MLP-CORRECT inner loop.
// R24 post-mortem: the locality mechanism WORKS (FETCH 144->73 MB via
// s_getreg(HW_REG_XCC_ID) pinning + stealing) but the inner loop had only 2
// gathers in flight (0.5 TB/s, VALU 16%, 186 us — latency x MLP collapse).
// R25 keeps the stealing shell and applies the PROVEN R22 MLP pattern at
// slice granularity: per wave, one node at a time, 16 items in flight via 4
// independent 512 B gathers (gi=lane>>4 item slot, li=lane&15 -> 8 B of the
// 128 B slice), shfl_xor(16,32) fold. Unit = (slice, 16 nodes): 4 nodes
// serial per wave, each 16-deep. Per-CU in flight ~= 32 waves x 4 x 512 B =
// 64 KB ~= R22's depth.
// PRE-COMMITTED: if agg2 >= 48 us, slicing is exhausted -> revert agg2 to the
// R22 agg_kernel<HID> form permanently and pivot to mgemm/build.
#define SL_CH    16                  // nodes per unit
#define SL_NSL   4                   // 128 B slices per 512 B row
#define SL_UNITS (NN / SL_CH)        // 2500 chunks per slice
__global__ __launch_bounds__(256) void agg2_sliced_kernel(
    const u16* __restrict__ hs, const int* __restrict__ cnt,
    const u16* __restrict__ col, u16* __restrict__ out,
    int* __restrict__ ctr)
{
    __shared__ int s_unit;
    const int tid  = threadIdx.x;
    const int lane = tid & 63;
    const int wave = tid >> 6;
    const int gi   = lane >> 4;          // item slot 0..3
    const int li   = lane & 15;          // 8 B sub-slice 0..15
    // physical XCD id (0..7) [HW-verified: learn_hip m09]
    const int xcc  = __builtin_amdgcn_s_getreg((31 << 11) | 20) & 7;
    const int pref = xcc & (SL_NSL - 1);

    for (;;) {
        if (tid == 0) {
            int u = -1;
            for (int s = 0; s < SL_NSL && u < 0; ++s) {
                int sl = (pref + s) & (SL_NSL - 1);
                int c  = atomicAdd(&ctr[sl], 1);
                if (c < SL_UNITS) u = sl * SL_UNITS + c;
            }
            s_unit = u;
        }
        __syncthreads();                 // s_unit visible to all
        const int unit = s_unit;
        if (unit < 0) break;             // uniform exit
        const int slice = unit / SL_UNITS;
        const int chunk = unit - slice * SL_UNITS;
        const u16* hsl = hs  + slice * 64 + li * 4;   // lane's 8 B in any row
        u16*       osl = out + slice * 64 + li * 4;
        const int nb = chunk * SL_CH + wave * 4;      // wave's 4 nodes

        for (int u2 = 0; u2 < 4; ++u2) {
            const int node = nb + u2;
            const int cn   = cnt[node];
            const int cb   = node << 6;
            float a0 = 0.0f, a1 = 0.0f, a2 = 0.0f, a3 = 0.0f;
            for (int base = 0; base <= cn; base += 16) {
                // phase 1: 16 item indices (4 slots x 4 instrs), no mem dep chain
                int idx[4]; bool val[4];
#pragma unroll
                for (int u = 0; u < 4; ++u) {
                    int it = base + u * 4 + gi;
                    val[u] = (it <= cn);
                    int v = node;
                    if (val[u] && it > 0) v = (int)col[cb + it - 1];
                    idx[u] = v;
                }
                // phase 2: 4 independent gathers — 16 items x 128 B in flight
                uint2 g[4];
#pragma unroll
                for (int u = 0; u < 4; ++u)
                    g[u] = *(const uint2*)(hsl + (size_t)idx[u] * HID);
                // phase 3: masked accumulate (4 f32 per lane)
#pragma unroll
                for (int u = 0; u < 4; ++u)
                    if (val[u]) {
                        a0 += __uint_as_float(g[u].x << 16);
                        a1 += __uint_as_float(g[u].x & 0xFFFF0000u);
                        a2 += __uint_as_float(g[u].y << 16);
                        a3 += __uint_as_float(g[u].y & 0xFFFF0000u);
                    }
            }
            // fold the 4 item slots (lane bits 4, 5)
            a0 += __shfl_xor(a0, 16); a0 += __shfl_xor(a0, 32);
            a1 += __shfl_xor(a1, 16); a1 += __shfl_xor(a1, 32);
            a2 += __shfl_xor(a2, 16); a2 += __shfl_xor(a2, 32);
            a3 += __shfl_xor(a3, 16); a3 += __shfl_xor(a3, 32);
            if (gi == 0) {               // lanes 0..15 cover the 128 B slice
                float dn = rsqrtf((float)(cn + 1));
                uint2 r;
                r.x = (unsigned)f2bf(a0 * dn) | ((unsigned)f2bf(a1 * dn) << 16);
                r.y = (unsigned)f2bf(a2 * dn) | ((unsigned)f2bf(a3 * dn) << 16);
                *(uint2*)(osl + (size_t)node * HID) = r;
            }
        }
        __syncthreads();                 // all waves done before s_unit reuse
    }
}

// ---------------------------------------------------------------------------
// Pool finalize: divide pooled sums by counts (binary search on sorted batch)
// + final linear.  (Pool phase 1 lives in mgemm<1>'s epilogue.)
__global__ __launch_bounds__(256) void pool_finalize_kernel(
    const float* __restrict__ pooled, const int* __restrict__ batch,
    const float* __restrict__ Wlin, const float* __restrict__ blin,
    float* __restrict__ out, int n_nodes)
{
    const int g = blockIdx.x;
    const int j = threadIdx.x;
    int lo = 0, hi = n_nodes;
    while (lo < hi) { int mid = (lo + hi) >> 1; if (batch[mid] < g) lo = mid + 1; else hi = mid; }
    const int start = lo;
    lo = start; hi = n_nodes;
    while (lo < hi) { int mid = (lo + hi) >> 1; if (batch[mid] < g + 1) lo = mid + 1; else hi = mid; }
    const int cnt = lo - start;

    float pv = pooled[(size_t)g * HID + j] / fmaxf((float)cnt, 1.0f);

    __shared__ float pl[HID];
    pl[j] = pv;
    __syncthreads();
    if (j < OUTC) {
        float o = blin[j];
        for (int k = 0; k < HID; ++k) o = fmaf(pl[k], Wlin[k * OUTC + j], o);
        out[g * OUTC + j] = o;
    }
}

// ---------------------------------------------------------------------------
extern "C" void kernel_launch(void* const* d_in, const int* in_sizes, int n_in,
                              void* d_out, int out_size, void* d_ws, size_t ws_size,
                              hipStream_t stream) {
    const float* x     = (const float*)d_in[0];
    const int*   ei    = (const int*)  d_in[1];   // [2, E]: row0 src, row1 dst
    const int*   batch = (const int*)  d_in[2];
    const float* W1    = (const float*)d_in[3];
    const float* b1    = (const float*)d_in[4];
    const float* W2    = (const float*)d_in[5];
    const float* b2    = (const float*)d_in[6];
    const float* Wlin  = (const float*)d_in[7];
    const float* blin  = (const float*)d_in[8];
    float* out = (float*)d_out;

    const int* src = ei;
    const int* dst = ei + EE;

    // workspace layout. [pooled|ctr|cnt] contiguous -> one hipMemsetAsync.
    char* p = (char*)d_ws;
    u16*   xs  = (u16*)p;   p += (size_t)NN * INC * sizeof(u16);    // 10.24 MB
    u16*   xab = (u16*)p;   p += (size_t)NN * INC * sizeof(u16);    // 10.24 MB
    u16*   h1s = (u16*)p;   p += (size_t)NN * HID * sizeof(u16);    // 20.48 MB
    u16*   a2b = (u16*)p;   p += (size_t)NN * HID * sizeof(u16);    // 20.48 MB
    u16*   w1h = (u16*)p;   p += (size_t)HID * INC * sizeof(u16);
    u16*   w1l = (u16*)p;   p += (size_t)HID * INC * sizeof(u16);
    u16*   w2h = (u16*)p;   p += (size_t)HID * HID * sizeof(u16);
    u16*   w2l = (u16*)p;   p += (size_t)HID * HID * sizeof(u16);
    char* zbase = p;                                         // memset region:
    float* pooled = (float*)p; p += (size_t)GG * HID * sizeof(float); //  pooled
    int* ctr    = (int*)p;  p += SL_NSL * sizeof(int);                //  ctr
    int* cnt    = (int*)p;  p += (size_t)NN * sizeof(int);            //  cnt
    size_t zbytes = (size_t)(p - zbase);
    u16* col    = (u16*)p;  p += (size_t)NN * CAP * sizeof(u16);      // 5.12 MB
    (void)ws_size; (void)n_in; (void)in_sizes; (void)out_size;

    const int TB = 256;
    const int e4     = EE / 4;                  // EE divisible by 4
    const int total4 = NN * INC / 4;
    const int build_threads = e4 + WTOT;
    const int nb_build = (build_threads + TB - 1) / TB;

    // structure pass (rebuilt every call; ws re-poisoned)
    hipMemsetAsync(zbase, 0, zbytes, stream);
    build_kernel<<<nb_build, TB, 0, stream>>>(src, dst, cnt, col, e4,
                                              W1, w1h, w1l, W2, w2h, w2l);
    // pre-scaled features (needs final cnt)
    xscale_kernel<<<(total4 + TB - 1) / TB, TB, 0, stream>>>(x, cnt, xs, total4);

    dim3 ggrid((NN + BM - 1) / BM, HID / BN);   // 313 x 2 blocks
    const int agg_blocks = (NN * 64 + TB - 1) / TB;   // one wave per node

    // layer 1: xab = bf16(d_n .* sum xs[idx]); h1s = bf16(d_m .* relu(xab@W1 + b1))
    agg_kernel<INC><<<agg_blocks, TB, 0, stream>>>(xs, cnt, col, xab, NN);
    mgemm_kernel<0><<<ggrid, 256, 0, stream>>>(xab, w1h, w1l, b1, cnt, h1s,
                                               batch, pooled, NN, INC);

    // layer 2: a2b via XCC-pinned sliced gather (persistent blocks + stealing)
    agg2_sliced_kernel<<<2048, TB, 0, stream>>>(h1s, cnt, col, a2b, ctr);
    mgemm_kernel<1><<<ggrid, 256, 0, stream>>>(a2b, w2h, w2l, b2, cnt, (u16*)nullptr,
                                               batch, pooled, NN, HID);

    // pool finalize (divide by counts) + linear
    pool_finalize_kernel<<<GG, 256, 0, stream>>>(pooled, batch, Wlin, blin, out, NN);
}

// Round 10
// 240.722 us; speedup vs baseline: 1.7193x; 1.7193x over previous
//
#include <hip/hip_runtime.h>

// Problem constants (fixed by the reference):
#define NN    40000
#define EE    640000
#define INC   128
#define HID   256
#define OUTC  10
#define GG    64
#define CAP   64        // CSR slot capacity per node (max in-degree << 64 for E/N=16)

typedef unsigned short u16;
typedef __attribute__((ext_vector_type(8))) short short8;   // 8 bf16 (4 VGPRs)
typedef __attribute__((ext_vector_type(4))) float f32x4;    // MFMA acc

__device__ __forceinline__ float bf2f(u16 h) {
    return __uint_as_float(((unsigned)h) << 16);
}
__device__ __forceinline__ u16 f2bf(float f) {   // round-to-nearest-even
    unsigned u = __float_as_uint(f);
    unsigned r = u + 0x7FFFu + ((u >> 16) & 1u);
    return (u16)(r >> 16);
}

// async global->LDS, 16 B per lane (mgemm staging only — R21's gather-to-LDS
// agg FAILED correctness; DO NOT RETRY).
__device__ __forceinline__ void gload_lds16(const u16* g, u16* l) {
    __builtin_amdgcn_global_load_lds(
        (const __attribute__((address_space(1))) unsigned int*)g,
        (__attribute__((address_space(3))) unsigned int*)l,
        16, 0, 0);
}

// ---------------------------------------------------------------------------
// build: ONE kernel, two independent segments:
//  [0, e4)       : edge pass — rank = cnt[dst]++ ; col[dst*CAP+rank]=src
//  [e4, e4+WTOT) : weight transpose + bf16 hi/lo split
#define WTOT (INC * HID + HID * HID)
__global__ void build_kernel(const int* __restrict__ src, const int* __restrict__ dst,
                             int* __restrict__ cnt, u16* __restrict__ col, int e4,
                             const float* __restrict__ W1, u16* __restrict__ w1h,
                             u16* __restrict__ w1l,
                             const float* __restrict__ W2, u16* __restrict__ w2h,
                             u16* __restrict__ w2l) {
    int i = blockIdx.x * blockDim.x + threadIdx.x;
    if (i < e4) {
        int4 d = ((const int4*)dst)[i];
        int4 s = ((const int4*)src)[i];
        int r0 = atomicAdd(&cnt[d.x], 1);
        int r1 = atomicAdd(&cnt[d.y], 1);
        int r2 = atomicAdd(&cnt[d.z], 1);
        int r3 = atomicAdd(&cnt[d.w], 1);
        if (r0 < CAP) col[(d.x << 6) + r0] = (u16)s.x;
        if (r1 < CAP) col[(d.y << 6) + r1] = (u16)s.y;
        if (r2 < CAP) col[(d.z << 6) + r2] = (u16)s.z;
        if (r3 < CAP) col[(d.w << 6) + r3] = (u16)s.w;
    } else if (i < e4 + WTOT) {
        int idx = i - e4;
        const float* W; u16 *Th, *Tl; int K;
        if (idx < INC * HID) { W = W1; Th = w1h; Tl = w1l; K = INC; }
        else { W = W2; Th = w2h; Tl = w2l; K = HID; idx -= INC * HID; }
        int k = idx >> 8;          // /256
        int n = idx & 255;
        float w = W[idx];          // idx == k*256 + n (row-major)
        u16 h = f2bf(w);
        float r = w - bf2f(h);
        Th[(size_t)n * K + k] = h;
        Tl[(size_t)n * K + k] = f2bf(r);
    }
}

// ---------------------------------------------------------------------------
// xs = bf16(rsqrt(cnt[n]+1) * x[n]) — pre-scaled features (R22). Runs after
// build (cnt final).
__global__ __launch_bounds__(256) void xscale_kernel(
    const float* __restrict__ x, const int* __restrict__ cnt,
    u16* __restrict__ xs, int total4) {
    int j = blockIdx.x * blockDim.x + threadIdx.x;   // one float4 per thread
    if (j >= total4) return;
    int n = j >> 5;                                  // 32 float4 per 128-row
    float dn = rsqrtf((float)(cnt[n] + 1));
    float4 v = ((const float4*)x)[j];
    ushort4 o;
    o.x = f2bf(v.x * dn); o.y = f2bf(v.y * dn);
    o.z = f2bf(v.z * dn); o.w = f2bf(v.w * dn);
    ((ushort4*)xs)[j] = o;
}

// ---------------------------------------------------------------------------
// MFMA GEMM. R26: BK=64 — halves barrier count (the m97-structure stall:
// each __syncthreads drains vmcnt(0) on cold A loads ~800cy; at BK=32 that
// was ~70% of block time: 16 drains vs ~1240cy MFMA/wave at K=256).
// LDS 48KB+4KB -> 3 blocks/CU (above m132's 2-block failure mode).
// Staging (R20 global_load_lds pattern at 128 B rows): 16 wave-loads/tile,
// each 8 rows x 8 chunk-slots; source chunk sv = su ^ (row&7); read slot
// (ks*4+qd) ^ (ln&7). C layout col=lane&15, row=qd*4+reg (verified).
//  MODE 0: store bf16(rsqrt(cnt[m]+1)*v) to Cout  (layer 1)
//  MODE 1: accumulate v into pooled[batch[m]][n]  (layer 2 + pool phase 1)
// FAILED, do not retry: R16 BM=64; R19 reg-staged LDS double-buffer.
#define BM 128
#define BN 128
#define BK 64
#define PGL 8    // max local graphs per 128-row tile (avg graph = 625 nodes)

template<int MODE>
__global__ __launch_bounds__(256) void mgemm_kernel(
    const u16* __restrict__ A,   // [M,K] bf16
    const u16* __restrict__ Bh,  // [256,K] bf16 (W^T hi)
    const u16* __restrict__ Bl,  // [256,K] bf16 (W^T lo)
    const float* __restrict__ bias,
    const int* __restrict__ cnt,
    u16* __restrict__ Cout,
    const int* __restrict__ batch, float* __restrict__ pooled,
    int M, int K)
{
    __shared__ __align__(16) u16 As [BM * BK];   // 16 KB, row = 128 B
    __shared__ __align__(16) u16 Bhs[BN * BK];   // 16 KB
    __shared__ __align__(16) u16 Bls[BN * BK];   // 16 KB
    __shared__ float ptile[MODE == 1 ? PGL * BN : 1];   // 4 KB in MODE 1 only

    const int tid  = threadIdx.x;
    const int lane = tid & 63;
    const int wave = tid >> 6;
    const int ln   = lane & 15;        // col within 16x16 tile
    const int qd   = lane >> 4;        // quad: k-unit for A/B frags, row-quad for C
    const int wm   = (wave & 1) * 64;  // wave m-offset in tile
    const int wn   = (wave >> 1) * 64; // wave n-offset in tile
    const int m0   = blockIdx.x * BM;
    const int n0   = blockIdx.y * BN;

    f32x4 acc[4][4];
#pragma unroll
    for (int i = 0; i < 4; ++i)
#pragma unroll
        for (int j = 0; j < 4; ++j) acc[i][j] = (f32x4)(0.0f);

    if (MODE == 1) {
        for (int t = tid; t < PGL * BN; t += 256) ptile[t] = 0.0f;
    }

    // staging lane roles: each wave-load covers 8 rows x 128 B (1 KB LDS)
    const int rl = lane >> 3;          // row within 8-row group (0..7)
    const int su = lane & 7;           // 16B chunk slot within row (0..7)

    for (int k0 = 0; k0 < K; k0 += BK) {
        // ---- stage chunk k0: 12 async wave-loads, no VGPR round trip ----
#pragma unroll
        for (int L = 0; L < 4; ++L) {
            int rloc = (wave * 4 + L) * 8 + rl;             // 0..127
            int sv   = (su ^ (rloc & 7)) * 8;               // swizzled src chunk
            int ga   = m0 + rloc; if (ga >= M) ga = M - 1;  // clamp; rows>=M never read back
            gload_lds16(A  + (size_t)ga * K          + k0 + sv, As  + (size_t)(wave * 4 + L) * 512);
            gload_lds16(Bh + (size_t)(n0 + rloc) * K + k0 + sv, Bhs + (size_t)(wave * 4 + L) * 512);
            gload_lds16(Bl + (size_t)(n0 + rloc) * K + k0 + sv, Bls + (size_t)(wave * 4 + L) * 512);
        }
        __syncthreads();   // drains vmcnt(0): tiles ready

        // ---- two 32-wide K-steps from the 64-wide chunk ----
#pragma unroll
        for (int ks = 0; ks < 2; ++ks) {
            const int fsw = ((ks * 4 + qd) ^ (ln & 7)) * 8;   // read slot (u16)
            short8 af[4], bfh[4], bfl[4];
#pragma unroll
            for (int t = 0; t < 4; ++t) {
                af[t]  = *(const short8*)(As  + (wm + t * 16 + ln) * BK + fsw);
                bfh[t] = *(const short8*)(Bhs + (wn + t * 16 + ln) * BK + fsw);
                bfl[t] = *(const short8*)(Bls + (wn + t * 16 + ln) * BK + fsw);
            }
#pragma unroll
            for (int ti = 0; ti < 4; ++ti)
#pragma unroll
                for (int tj = 0; tj < 4; ++tj) {
                    acc[ti][tj] = __builtin_amdgcn_mfma_f32_16x16x32_bf16(
                        af[ti], bfh[tj], acc[ti][tj], 0, 0, 0);
                    acc[ti][tj] = __builtin_amdgcn_mfma_f32_16x16x32_bf16(
                        af[ti], bfl[tj], acc[ti][tj], 0, 0, 0);
                }
        }
        __syncthreads();   // frag reads done before next chunk overwrites
    }

    // ---- epilogue: C layout col=lane&15, row=qd*4+reg ----
    float bcol[4];
#pragma unroll
    for (int tj = 0; tj < 4; ++tj) bcol[tj] = bias[n0 + wn + tj * 16 + ln];

    if (MODE == 0) {
#pragma unroll
        for (int ti = 0; ti < 4; ++ti) {
#pragma unroll
            for (int r = 0; r < 4; ++r) {
                int row = m0 + wm + ti * 16 + qd * 4 + r;
                if (row < M) {
                    float dm = rsqrtf((float)(cnt[row] + 1));
                    u16* crow = Cout + (size_t)row * HID;
#pragma unroll
                    for (int tj = 0; tj < 4; ++tj) {
                        float v = fmaxf(acc[ti][tj][r] + bcol[tj], 0.0f);
                        crow[n0 + wn + tj * 16 + ln] = f2bf(v * dm);
                    }
                }
            }
        }
    } else {
        // cache graph ids of this thread's 16 rows
        int bg[16];
#pragma unroll
        for (int ti = 0; ti < 4; ++ti)
#pragma unroll
            for (int r = 0; r < 4; ++r) {
                int row = m0 + wm + ti * 16 + qd * 4 + r;
                bg[ti * 4 + r] = (row < M) ? batch[row] : -1;
            }
        const int g_lo = batch[m0];
        const int g_hi = batch[min(m0 + BM, M) - 1];
        for (int g = g_lo; g <= g_hi; ++g) {
            float cs[4] = {0.0f, 0.0f, 0.0f, 0.0f};
#pragma unroll
            for (int ti = 0; ti < 4; ++ti)
#pragma unroll
                for (int r = 0; r < 4; ++r)
                    if (bg[ti * 4 + r] == g) {
#pragma unroll
                        for (int tj = 0; tj < 4; ++tj)
                            cs[tj] += fmaxf(acc[ti][tj][r] + bcol[tj], 0.0f);
                    }
            // fold the 4 qd lanes holding the same column (lane bits 16, 32)
#pragma unroll
            for (int tj = 0; tj < 4; ++tj) {
                cs[tj] += __shfl_xor(cs[tj], 16);
                cs[tj] += __shfl_xor(cs[tj], 32);
            }
            if (qd == 0) {
                int gl = g - g_lo;
#pragma unroll
                for (int tj = 0; tj < 4; ++tj) {
                    int c = wn + tj * 16 + ln;
                    if (gl < PGL) atomicAdd(&ptile[gl * BN + c], cs[tj]);
                    else atomicAdd(&pooled[(size_t)g * HID + n0 + c], cs[tj]);
                }
            }
        }
        __syncthreads();
        const int g0 = batch[m0];
        for (int t = tid; t < PGL * BN; t += 256) {
            float v = ptile[t];
            if (v != 0.0f) {
                int gl = t / BN, c = t % BN;
                atomicAdd(&pooled[(size_t)(g0 + gl) * HID + n0 + c], v);
            }
        }
    }
}

// ---------------------------------------------------------------------------
// Aggregation (both layers): PROVEN R22 wave-per-node gather — PERMANENT.
// out[n] = bf16(rsqrt(cnt[n]+1) * sum_items hs[idx]).
// agg2 sits at ~85% of its FETCH x rate floor (144 MB / 3.5 TB/s = 41 us).
// CLOSED avenues (do not retry): R8 UFx2, R10 2-waves/node, R13 src-partition,
// R19 shfl-hoist (neutral), R21 gather-to-LDS (broken), R23 %8-slice (mapping
// wrong), R24/R25 XCC-pinned slicing (locality works — FETCH 73 MB — but
// slice-granularity gathers collapse MLP: 1/4 bytes per instr, net 4x slower).
template<int F>
__global__ __launch_bounds__(256) void agg_kernel(
    const u16* __restrict__ hs, const int* __restrict__ cnt,
    const u16* __restrict__ col, u16* __restrict__ out, int n_nodes)
{
    constexpr int L  = F / 8;                   // lanes per item (16 or 32)
    constexpr int G  = 64 / L;                  // items per batch (4 or 2)
    constexpr int UF = 16 / G;                  // batches per iteration
    const int lane = threadIdx.x & 63;
    const int n    = (blockIdx.x * blockDim.x + threadIdx.x) >> 6;  // wave id
    if (n >= n_nodes) return;
    const int li = lane % L;
    const int gi = lane / L;

    const int base0 = n << 6;                   // n*CAP
    const int total = 1 + cnt[n];               // self + edges

    float acc[8];
#pragma unroll
    for (int i = 0; i < 8; ++i) acc[i] = 0.0f;

    for (int base = 0; base < total; base += G * UF) {
        int  idxs[UF];
        bool valid[UF];
#pragma unroll
        for (int u = 0; u < UF; ++u) {
            int it = base + u * G + gi;
            valid[u] = (it < total);
            idxs[u] = 0;
            if (valid[u]) idxs[u] = (it == 0) ? n : (int)col[base0 + it - 1];
        }
        uint4 w[UF];
#pragma unroll
        for (int u = 0; u < UF; ++u)
            if (valid[u])
                w[u] = *(const uint4*)(hs + (size_t)idxs[u] * F + li * 8);
#pragma unroll
        for (int u = 0; u < UF; ++u)
            if (valid[u]) {
                unsigned uu[4] = {w[u].x, w[u].y, w[u].z, w[u].w};
#pragma unroll
                for (int q = 0; q < 4; ++q) {
                    acc[2 * q]     += __uint_as_float(uu[q] << 16);
                    acc[2 * q + 1] += __uint_as_float(uu[q] & 0xFFFF0000u);
                }
            }
    }

#pragma unroll
    for (int off = 32; off >= L; off >>= 1)
#pragma unroll
        for (int i = 0; i < 8; ++i)
            acc[i] += __shfl_xor(acc[i], off);

    if (gi == 0) {
        float d = rsqrtf((float)total);
        unsigned r[4];
#pragma unroll
        for (int q = 0; q < 4; ++q) {
            unsigned l16 = (unsigned)f2bf(acc[2 * q] * d);
            unsigned h16 = (unsigned)f2bf(acc[2 * q + 1] * d);
            r[q] = l16 | (h16 << 16);
        }
        *(uint4*)(out + (size_t)n * F + li * 8) = make_uint4(r[0], r[1], r[2], r[3]);
    }
}

// ---------------------------------------------------------------------------
// Pool finalize: divide pooled sums by counts (binary search on sorted batch)
// + final linear.  (Pool phase 1 lives in mgemm<1>'s epilogue.)
__global__ __launch_bounds__(256) void pool_finalize_kernel(
    const float* __restrict__ pooled, const int* __restrict__ batch,
    const float* __restrict__ Wlin, const float* __restrict__ blin,
    float* __restrict__ out, int n_nodes)
{
    const int g = blockIdx.x;
    const int j = threadIdx.x;
    int lo = 0, hi = n_nodes;
    while (lo < hi) { int mid = (lo + hi) >> 1; if (batch[mid] < g) lo = mid + 1; else hi = mid; }
    const int start = lo;
    lo = start; hi = n_nodes;
    while (lo < hi) { int mid = (lo + hi) >> 1; if (batch[mid] < g + 1) lo = mid + 1; else hi = mid; }
    const int cnt = lo - start;

    float pv = pooled[(size_t)g * HID + j] / fmaxf((float)cnt, 1.0f);

    __shared__ float pl[HID];
    pl[j] = pv;
    __syncthreads();
    if (j < OUTC) {
        float o = blin[j];
        for (int k = 0; k < HID; ++k) o = fmaf(pl[k], Wlin[k * OUTC + j], o);
        out[g * OUTC + j] = o;
    }
}

// ---------------------------------------------------------------------------
extern "C" void kernel_launch(void* const* d_in, const int* in_sizes, int n_in,
                              void* d_out, int out_size, void* d_ws, size_t ws_size,
                              hipStream_t stream) {
    const float* x     = (const float*)d_in[0];
    const int*   ei    = (const int*)  d_in[1];   // [2, E]: row0 src, row1 dst
    const int*   batch = (const int*)  d_in[2];
    const float* W1    = (const float*)d_in[3];
    const float* b1    = (const float*)d_in[4];
    const float* W2    = (const float*)d_in[5];
    const float* b2    = (const float*)d_in[6];
    const float* Wlin  = (const float*)d_in[7];
    const float* blin  = (const float*)d_in[8];
    float* out = (float*)d_out;

    const int* src = ei;
    const int* dst = ei + EE;

    // workspace layout. [pooled|cnt] contiguous -> zeroed by one hipMemsetAsync.
    char* p = (char*)d_ws;
    u16*   xs  = (u16*)p;   p += (size_t)NN * INC * sizeof(u16);    // 10.24 MB
    u16*   xab = (u16*)p;   p += (size_t)NN * INC * sizeof(u16);    // 10.24 MB
    u16*   h1s = (u16*)p;   p += (size_t)NN * HID * sizeof(u16);    // 20.48 MB
    u16*   a2b = (u16*)p;   p += (size_t)NN * HID * sizeof(u16);    // 20.48 MB
    u16*   w1h = (u16*)p;   p += (size_t)HID * INC * sizeof(u16);
    u16*   w1l = (u16*)p;   p += (size_t)HID * INC * sizeof(u16);
    u16*   w2h = (u16*)p;   p += (size_t)HID * HID * sizeof(u16);
    u16*   w2l = (u16*)p;   p += (size_t)HID * HID * sizeof(u16);
    char* zbase = p;                                         // memset region:
    float* pooled = (float*)p; p += (size_t)GG * HID * sizeof(float); //  pooled
    int* cnt    = (int*)p;  p += (size_t)NN * sizeof(int);            //  cnt
    size_t zbytes = (size_t)(p - zbase);
    u16* col    = (u16*)p;  p += (size_t)NN * CAP * sizeof(u16);      // 5.12 MB
    (void)ws_size; (void)n_in; (void)in_sizes; (void)out_size;

    const int TB = 256;
    const int e4     = EE / 4;                  // EE divisible by 4
    const int total4 = NN * INC / 4;
    const int build_threads = e4 + WTOT;
    const int nb_build = (build_threads + TB - 1) / TB;

    // structure pass (rebuilt every call; ws re-poisoned)
    hipMemsetAsync(zbase, 0, zbytes, stream);
    build_kernel<<<nb_build, TB, 0, stream>>>(src, dst, cnt, col, e4,
                                              W1, w1h, w1l, W2, w2h, w2l);
    // pre-scaled features (needs final cnt)
    xscale_kernel<<<(total4 + TB - 1) / TB, TB, 0, stream>>>(x, cnt, xs, total4);

    dim3 ggrid((NN + BM - 1) / BM, HID / BN);   // 313 x 2 blocks
    const int agg_blocks = (NN * 64 + TB - 1) / TB;   // one wave per node

    // layer 1: xab = bf16(d_n .* sum xs[idx]); h1s = bf16(d_m .* relu(xab@W1 + b1))
    agg_kernel<INC><<<agg_blocks, TB, 0, stream>>>(xs, cnt, col, xab, NN);
    mgemm_kernel<0><<<ggrid, 256, 0, stream>>>(xab, w1h, w1l, b1, cnt, h1s,
                                               batch, pooled, NN, INC);

    // layer 2: a2b = bf16(d_n .* (h1s self + gather));
    // gemm2 fuses relu(a2b@W2 + b2) with pool phase 1 (conflict-free reduction)
    agg_kernel<HID><<<agg_blocks, TB, 0, stream>>>(h1s, cnt, col, a2b, NN);
    mgemm_kernel<1><<<ggrid, 256, 0, stream>>>(a2b, w2h, w2l, b2, cnt, (u16*)nullptr,
                                               batch, pooled, NN, HID);

    // pool finalize (divide by counts) + linear
    pool_finalize_kernel<<<GG, 256, 0, stream>>>(pooled, batch, Wlin, blin, out, NN);
}

// Round 12
// 232.105 us; speedup vs baseline: 1.7831x; 1.0371x over previous
//
#include <hip/hip_runtime.h>

// Problem constants (fixed by the reference):
#define NN    40000
#define EE    640000
#define INC   128
#define HID   256
#define OUTC  10
#define GG    64
#define CAP   64        // CSR slot capacity per node (max in-degree << 64 for E/N=16)

typedef unsigned short u16;
typedef __attribute__((ext_vector_type(8))) short short8;   // 8 bf16 (4 VGPRs)
typedef __attribute__((ext_vector_type(4))) float f32x4;    // MFMA acc

__device__ __forceinline__ float bf2f(u16 h) {
    return __uint_as_float(((unsigned)h) << 16);
}
__device__ __forceinline__ u16 f2bf(float f) {   // round-to-nearest-even
    unsigned u = __float_as_uint(f);
    unsigned r = u + 0x7FFFu + ((u >> 16) & 1u);
    return (u16)(r >> 16);
}

// async global->LDS, 16 B per lane (mgemm staging only — R21's gather-to-LDS
// agg FAILED correctness; DO NOT RETRY).
__device__ __forceinline__ void gload_lds16(const u16* g, u16* l) {
    __builtin_amdgcn_global_load_lds(
        (const __attribute__((address_space(1))) unsigned int*)g,
        (__attribute__((address_space(3))) unsigned int*)l,
        16, 0, 0);
}

// ---------------------------------------------------------------------------
// build: ONE kernel, three independent segments:
//  [0, e4)              : edge pass — rank = cnt[dst]++ ; col[dst*CAP+rank]=src
//  [e4, e4+WTOT)        : weight transpose, SINGLE bf16 (R28 — R27's version
//                         had an OOB indexing bug in the W2 branch: used
//                         idx+INC*HID after idx was already decremented.
//                         absmax 9.1e-2 was the BUG, not bf16 rounding.
//                         Correct index is the LOCAL idx.)
//  [e4+WTOT, +total4)   : xq = bf16(x), 4 elems/thread
#define WTOT (INC * HID + HID * HID)
__global__ void build_kernel(const int* __restrict__ src, const int* __restrict__ dst,
                             int* __restrict__ cnt, u16* __restrict__ col, int e4,
                             const float* __restrict__ W1, u16* __restrict__ w1h,
                             const float* __restrict__ W2, u16* __restrict__ w2h,
                             const float* __restrict__ x, u16* __restrict__ xq,
                             int total4) {
    int i = blockIdx.x * blockDim.x + threadIdx.x;
    if (i < e4) {
        int4 d = ((const int4*)dst)[i];
        int4 s = ((const int4*)src)[i];
        int r0 = atomicAdd(&cnt[d.x], 1);
        int r1 = atomicAdd(&cnt[d.y], 1);
        int r2 = atomicAdd(&cnt[d.z], 1);
        int r3 = atomicAdd(&cnt[d.w], 1);
        if (r0 < CAP) col[(d.x << 6) + r0] = (u16)s.x;
        if (r1 < CAP) col[(d.y << 6) + r1] = (u16)s.y;
        if (r2 < CAP) col[(d.z << 6) + r2] = (u16)s.z;
        if (r3 < CAP) col[(d.w << 6) + r3] = (u16)s.w;
    } else if (i < e4 + WTOT) {
        int idx = i - e4;
        const float* W; u16* Th; int K;
        if (idx < INC * HID) { W = W1; Th = w1h; K = INC; }
        else { W = W2; Th = w2h; K = HID; idx -= INC * HID; }
        int k = idx >> 8;          // /256
        int n = idx & 255;
        Th[(size_t)n * K + k] = f2bf(W[idx]);   // idx == k*256 + n (row-major, LOCAL)
    } else {
        int j = i - e4 - WTOT;
        if (j < total4) {
            float4 v = ((const float4*)x)[j];
            ushort4 o;
            o.x = f2bf(v.x); o.y = f2bf(v.y);
            o.z = f2bf(v.z); o.w = f2bf(v.w);
            ((ushort4*)xq)[j] = o;
        }
    }
}

// ---------------------------------------------------------------------------
// MFMA GEMM. R27/R28: SINGLE-bf16 weights — half the MFMA work, half the B
// staging, LDS 36 KB -> 4 blocks/CU. R26's BK=64 kept (240.7 <= 241.3).
// Error budget for dropping the lo-weight path: activations already
// single-bf16 (4 rounding stages); mean-pool averages ~625 nodes (/25 on
// per-node std); measured absmax with hi/lo was 4.88e-4 vs 1.62e-3 threshold.
// C[M, 256] = A[M,K](bf16) @ Wh[K,256] (stored transposed [256][K] bf16).
//  MODE 0: store bf16(rsqrt(cnt[m]+1)*v) to Cout  (layer 1)
//  MODE 1: accumulate v into pooled[batch[m]][n]  (layer 2 + pool phase 1)
// Staging: global_load_lds width=16, LINEAR LDS, both-sides chunk XOR swizzle
//   (src chunk su^(row&7); read slot (ks*4+qd)^(ln&7)).
// FAILED, do not retry: R16 BM=64; R19 reg-staged LDS dbuf; R26 BK=64 gave
// only -1 us (barrier drain was NOT the mgemm bottleneck — pair is small).
#define BM 128
#define BN 128
#define BK 64
#define PGL 8    // max local graphs per 128-row tile (avg graph = 625 nodes)

template<int MODE>
__global__ __launch_bounds__(256) void mgemm_kernel(
    const u16* __restrict__ A,   // [M,K] bf16
    const u16* __restrict__ Bh,  // [256,K] bf16 (W^T)
    const float* __restrict__ bias,
    const int* __restrict__ cnt,
    u16* __restrict__ Cout,
    const int* __restrict__ batch, float* __restrict__ pooled,
    int M, int K)
{
    __shared__ __align__(16) u16 As [BM * BK];   // 16 KB, row = 128 B
    __shared__ __align__(16) u16 Bhs[BN * BK];   // 16 KB
    __shared__ float ptile[MODE == 1 ? PGL * BN : 1];   // 4 KB in MODE 1 only

    const int tid  = threadIdx.x;
    const int lane = tid & 63;
    const int wave = tid >> 6;
    const int ln   = lane & 15;        // col within 16x16 tile
    const int qd   = lane >> 4;        // quad: k-unit for A/B frags, row-quad for C
    const int wm   = (wave & 1) * 64;  // wave m-offset in tile
    const int wn   = (wave >> 1) * 64; // wave n-offset in tile
    const int m0   = blockIdx.x * BM;
    const int n0   = blockIdx.y * BN;

    f32x4 acc[4][4];
#pragma unroll
    for (int i = 0; i < 4; ++i)
#pragma unroll
        for (int j = 0; j < 4; ++j) acc[i][j] = (f32x4)(0.0f);

    if (MODE == 1) {
        for (int t = tid; t < PGL * BN; t += 256) ptile[t] = 0.0f;
    }

    // staging lane roles: each wave-load covers 8 rows x 128 B (1 KB LDS)
    const int rl = lane >> 3;          // row within 8-row group (0..7)
    const int su = lane & 7;           // 16B chunk slot within row (0..7)

    for (int k0 = 0; k0 < K; k0 += BK) {
        // ---- stage chunk k0: 8 async wave-loads, no VGPR round trip ----
#pragma unroll
        for (int L = 0; L < 4; ++L) {
            int rloc = (wave * 4 + L) * 8 + rl;             // 0..127
            int sv   = (su ^ (rloc & 7)) * 8;               // swizzled src chunk
            int ga   = m0 + rloc; if (ga >= M) ga = M - 1;  // clamp; rows>=M never read back
            gload_lds16(A  + (size_t)ga * K          + k0 + sv, As  + (size_t)(wave * 4 + L) * 512);
            gload_lds16(Bh + (size_t)(n0 + rloc) * K + k0 + sv, Bhs + (size_t)(wave * 4 + L) * 512);
        }
        __syncthreads();   // drains vmcnt(0): tiles ready

        // ---- two 32-wide K-steps from the 64-wide chunk ----
#pragma unroll
        for (int ks = 0; ks < 2; ++ks) {
            const int fsw = ((ks * 4 + qd) ^ (ln & 7)) * 8;   // read slot (u16)
            short8 af[4], bfh[4];
#pragma unroll
            for (int t = 0; t < 4; ++t) {
                af[t]  = *(const short8*)(As  + (wm + t * 16 + ln) * BK + fsw);
                bfh[t] = *(const short8*)(Bhs + (wn + t * 16 + ln) * BK + fsw);
            }
#pragma unroll
            for (int ti = 0; ti < 4; ++ti)
#pragma unroll
                for (int tj = 0; tj < 4; ++tj)
                    acc[ti][tj] = __builtin_amdgcn_mfma_f32_16x16x32_bf16(
                        af[ti], bfh[tj], acc[ti][tj], 0, 0, 0);
        }
        __syncthreads();   // frag reads done before next chunk overwrites
    }

    // ---- epilogue: C layout col=lane&15, row=qd*4+reg ----
    float bcol[4];
#pragma unroll
    for (int tj = 0; tj < 4; ++tj) bcol[tj] = bias[n0 + wn + tj * 16 + ln];

    if (MODE == 0) {
#pragma unroll
        for (int ti = 0; ti < 4; ++ti) {
#pragma unroll
            for (int r = 0; r < 4; ++r) {
                int row = m0 + wm + ti * 16 + qd * 4 + r;
                if (row < M) {
                    float dm = rsqrtf((float)(cnt[row] + 1));
                    u16* crow = Cout + (size_t)row * HID;
#pragma unroll
                    for (int tj = 0; tj < 4; ++tj) {
                        float v = fmaxf(acc[ti][tj][r] + bcol[tj], 0.0f);
                        crow[n0 + wn + tj * 16 + ln] = f2bf(v * dm);
                    }
                }
            }
        }
    } else {
        // cache graph ids of this thread's 16 rows
        int bg[16];
#pragma unroll
        for (int ti = 0; ti < 4; ++ti)
#pragma unroll
            for (int r = 0; r < 4; ++r) {
                int row = m0 + wm + ti * 16 + qd * 4 + r;
                bg[ti * 4 + r] = (row < M) ? batch[row] : -1;
            }
        const int g_lo = batch[m0];
        const int g_hi = batch[min(m0 + BM, M) - 1];
        for (int g = g_lo; g <= g_hi; ++g) {
            float cs[4] = {0.0f, 0.0f, 0.0f, 0.0f};
#pragma unroll
            for (int ti = 0; ti < 4; ++ti)
#pragma unroll
                for (int r = 0; r < 4; ++r)
                    if (bg[ti * 4 + r] == g) {
#pragma unroll
                        for (int tj = 0; tj < 4; ++tj)
                            cs[tj] += fmaxf(acc[ti][tj][r] + bcol[tj], 0.0f);
                    }
            // fold the 4 qd lanes holding the same column (lane bits 16, 32)
#pragma unroll
            for (int tj = 0; tj < 4; ++tj) {
                cs[tj] += __shfl_xor(cs[tj], 16);
                cs[tj] += __shfl_xor(cs[tj], 32);
            }
            if (qd == 0) {
                int gl = g - g_lo;
#pragma unroll
                for (int tj = 0; tj < 4; ++tj) {
                    int c = wn + tj * 16 + ln;
                    if (gl < PGL) atomicAdd(&ptile[gl * BN + c], cs[tj]);
                    else atomicAdd(&pooled[(size_t)g * HID + n0 + c], cs[tj]);
                }
            }
        }
        __syncthreads();
        const int g0 = batch[m0];
        for (int t = tid; t < PGL * BN; t += 256) {
            float v = ptile[t];
            if (v != 0.0f) {
                int gl = t / BN, c = t % BN;
                atomicAdd(&pooled[(size_t)(g0 + gl) * HID + n0 + c], v);
            }
        }
    }
}

// ---------------------------------------------------------------------------
// Aggregation, wave-per-node — PROVEN R1/R3 structure, PERMANENT.
// PERDIS=true  (layer 1): out[n] = bf16(d_n * sum_items d_idx * xq[idx])
// PERDIS=false (layer 2): out[n] = bf16(d_n * sum_items hs[idx])
// agg2 sits at ~85% of its FETCH x rate floor (144 MB / 3.5 TB/s = 41 us).
// CLOSED avenues (do not retry): R8 UFx2, R10 2-waves/node, R13 src-partition,
// R19 shfl-hoist (neutral), R21 gather-to-LDS (broken), R22 xscale split
// (neutral-negative), R23 %8-slice (mapping wrong), R24/R25 XCC-pinned slicing
// (locality works — FETCH 73 MB — but slice-granularity gathers collapse MLP).
template<int F, bool PERDIS>
__global__ __launch_bounds__(256) void agg_kernel(
    const u16* __restrict__ hs, const int* __restrict__ cnt,
    const u16* __restrict__ col, u16* __restrict__ out, int n_nodes)
{
    constexpr int L  = F / 8;                   // lanes per item (16 or 32)
    constexpr int G  = 64 / L;                  // items per batch (4 or 2)
    constexpr int UF = 16 / G;                  // batches per iteration
    const int lane = threadIdx.x & 63;
    const int n    = (blockIdx.x * blockDim.x + threadIdx.x) >> 6;  // wave id
    if (n >= n_nodes) return;
    const int li = lane % L;
    const int gi = lane / L;

    const int base0 = n << 6;                   // n*CAP
    const int total = 1 + cnt[n];               // self + edges

    float acc[8];
#pragma unroll
    for (int i = 0; i < 8; ++i) acc[i] = 0.0f;

    for (int base = 0; base < total; base += G * UF) {
        int  idxs[UF];
        bool valid[UF];
        // phase 1: independent col-index loads (broadcast within group)
#pragma unroll
        for (int u = 0; u < UF; ++u) {
            int it = base + u * G + gi;
            valid[u] = (it < total);
            idxs[u] = 0;
            if (valid[u]) idxs[u] = (it == 0) ? n : (int)col[base0 + it - 1];
        }
        // phase 2: independent row gathers (+ cnt gathers for PERDIS)
        uint4 w[UF];
        int   cv[UF];
#pragma unroll
        for (int u = 0; u < UF; ++u)
            if (valid[u]) {
                w[u] = *(const uint4*)(hs + (size_t)idxs[u] * F + li * 8);
                if (PERDIS) cv[u] = cnt[idxs[u]];
            }
        // phase 3: accumulate
#pragma unroll
        for (int u = 0; u < UF; ++u)
            if (valid[u]) {
                float d = PERDIS ? rsqrtf((float)(cv[u] + 1)) : 1.0f;
                unsigned uu[4] = {w[u].x, w[u].y, w[u].z, w[u].w};
#pragma unroll
                for (int q = 0; q < 4; ++q) {
                    if (PERDIS) {
                        acc[2 * q]     = fmaf(d, __uint_as_float(uu[q] << 16), acc[2 * q]);
                        acc[2 * q + 1] = fmaf(d, __uint_as_float(uu[q] & 0xFFFF0000u), acc[2 * q + 1]);
                    } else {
                        acc[2 * q]     += __uint_as_float(uu[q] << 16);
                        acc[2 * q + 1] += __uint_as_float(uu[q] & 0xFFFF0000u);
                    }
                }
            }
    }

    // combine the G partial groups (lane strides L..32)
#pragma unroll
    for (int off = 32; off >= L; off >>= 1)
#pragma unroll
        for (int i = 0; i < 8; ++i)
            acc[i] += __shfl_xor(acc[i], off);

    if (gi == 0) {
        float d = rsqrtf((float)total);         // total == cnt[n]+1
        unsigned r[4];
#pragma unroll
        for (int q = 0; q < 4; ++q) {
            unsigned l16 = (unsigned)f2bf(acc[2 * q] * d);
            unsigned h16 = (unsigned)f2bf(acc[2 * q + 1] * d);
            r[q] = l16 | (h16 << 16);
        }
        *(uint4*)(out + (size_t)n * F + li * 8) = make_uint4(r[0], r[1], r[2], r[3]);
    }
}

// ---------------------------------------------------------------------------
// Pool finalize: divide pooled sums by counts (binary search on sorted batch)
// + final linear.  (Pool phase 1 lives in mgemm<1>'s epilogue.)
__global__ __launch_bounds__(256) void pool_finalize_kernel(
    const float* __restrict__ pooled, const int* __restrict__ batch,
    const float* __restrict__ Wlin, const float* __restrict__ blin,
    float* __restrict__ out, int n_nodes)
{
    const int g = blockIdx.x;
    const int j = threadIdx.x;
    int lo = 0, hi = n_nodes;
    while (lo < hi) { int mid = (lo + hi) >> 1; if (batch[mid] < g) lo = mid + 1; else hi = mid; }
    const int start = lo;
    lo = start; hi = n_nodes;
    while (lo < hi) { int mid = (lo + hi) >> 1; if (batch[mid] < g + 1) lo = mid + 1; else hi = mid; }
    const int cnt = lo - start;

    float pv = pooled[(size_t)g * HID + j] / fmaxf((float)cnt, 1.0f);

    __shared__ float pl[HID];
    pl[j] = pv;
    __syncthreads();
    if (j < OUTC) {
        float o = blin[j];
        for (int k = 0; k < HID; ++k) o = fmaf(pl[k], Wlin[k * OUTC + j], o);
        out[g * OUTC + j] = o;
    }
}

// ---------------------------------------------------------------------------
extern "C" void kernel_launch(void* const* d_in, const int* in_sizes, int n_in,
                              void* d_out, int out_size, void* d_ws, size_t ws_size,
                              hipStream_t stream) {
    const float* x     = (const float*)d_in[0];
    const int*   ei    = (const int*)  d_in[1];   // [2, E]: row0 src, row1 dst
    const int*   batch = (const int*)  d_in[2];
    const float* W1    = (const float*)d_in[3];
    const float* b1    = (const float*)d_in[4];
    const float* W2    = (const float*)d_in[5];
    const float* b2    = (const float*)d_in[6];
    const float* Wlin  = (const float*)d_in[7];
    const float* blin  = (const float*)d_in[8];
    float* out = (float*)d_out;

    const int* src = ei;
    const int* dst = ei + EE;

    // workspace layout. [pooled|cnt] contiguous -> zeroed by one hipMemsetAsync.
    char* p = (char*)d_ws;
    u16*   xq  = (u16*)p;   p += (size_t)NN * INC * sizeof(u16);    // 10.24 MB
    u16*   xab = (u16*)p;   p += (size_t)NN * INC * sizeof(u16);    // 10.24 MB
    u16*   h1s = (u16*)p;   p += (size_t)NN * HID * sizeof(u16);    // 20.48 MB
    u16*   a2b = (u16*)p;   p += (size_t)NN * HID * sizeof(u16);    // 20.48 MB
    u16*   w1h = (u16*)p;   p += (size_t)HID * INC * sizeof(u16);
    u16*   w2h = (u16*)p;   p += (size_t)HID * HID * sizeof(u16);
    char* zbase = p;                                         // memset region:
    float* pooled = (float*)p; p += (size_t)GG * HID * sizeof(float); //  pooled
    int* cnt    = (int*)p;  p += (size_t)NN * sizeof(int);            //  cnt
    size_t zbytes = (size_t)(p - zbase);
    u16* col    = (u16*)p;  p += (size_t)NN * CAP * sizeof(u16);      // 5.12 MB
    (void)ws_size; (void)n_in; (void)in_sizes; (void)out_size;

    const int TB = 256;
    const int e4     = EE / 4;                  // EE divisible by 4
    const int total4 = NN * INC / 4;
    const int build_threads = e4 + WTOT + total4;
    const int nb_build = (build_threads + TB - 1) / TB;

    // ONE fused structure+quantize pass (rebuilt every call; ws re-poisoned)
    hipMemsetAsync(zbase, 0, zbytes, stream);
    build_kernel<<<nb_build, TB, 0, stream>>>(src, dst, cnt, col, e4,
                                              W1, w1h, W2, w2h, x, xq, total4);

    dim3 ggrid((NN + BM - 1) / BM, HID / BN);   // 313 x 2 blocks
    const int agg_blocks = (NN * 64 + TB - 1) / TB;   // one wave per node

    // layer 1: xab = bf16(d_n .* sum d_idx*xq[idx]); h1s = bf16(d_m .* relu(xab@W1 + b1))
    agg_kernel<INC, true><<<agg_blocks, TB, 0, stream>>>(xq, cnt, col, xab, NN);
    mgemm_kernel<0><<<ggrid, 256, 0, stream>>>(xab, w1h, b1, cnt, h1s,
                                               batch, pooled, NN, INC);

    // layer 2: a2b = bf16(d_n .* (h1s self + gather));
    // gemm2 fuses relu(a2b@W2 + b2) with pool phase 1 (conflict-free reduction)
    agg_kernel<HID, false><<<agg_blocks, TB, 0, stream>>>(h1s, cnt, col, a2b, NN);
    mgemm_kernel<1><<<ggrid, 256, 0, stream>>>(a2b, w2h, b2, cnt, (u16*)nullptr,
                                               batch, pooled, NN, HID);

    // pool finalize (divide by counts) + linear
    pool_finalize_kernel<<<GG, 256, 0, stream>>>(pooled, batch, Wlin, blin, out, NN);
}